// Round 1
// baseline (549.781 us; speedup 1.0000x reference)
//
#include <hip/hip_runtime.h>
#include <hip/hip_bf16.h>
#include <stdint.h>

#define LOG2E 1.44269504088896340736f

typedef float f32x4 __attribute__((ext_vector_type(4)));
typedef __bf16 bf16x8 __attribute__((ext_vector_type(8)));

__device__ __forceinline__ void g2lds16(const void* g, void* l) {
  __builtin_amdgcn_global_load_lds(
      (__attribute__((address_space(1))) unsigned int*)g,
      (__attribute__((address_space(3))) unsigned int*)l,
      16, 0, 0);
}

__device__ __forceinline__ unsigned short f2bf_u(float f) {
  __bf16 h = (__bf16)f;
  return __builtin_bit_cast(unsigned short, h);
}

// ---------------------------------------------------------------------------
// fused_prep: 640 blocks. pid<512: prep_hidden (barrier-free, 4 waves x 4
// rows, XCD-colocated row mapping). pid>=512: prep_w grid-stride bf16 cast.
// Block 0 additionally zeroes the mega-kernel control block (ticket counter,
// stats counter, 512 gemm-tile flags) — visible to the next launch via the
// kernel-boundary release.
// ---------------------------------------------------------------------------
__global__ void __launch_bounds__(256) fused_prep(
    const float* __restrict__ hidden, const float* __restrict__ U,
    const float* __restrict__ V, const float* __restrict__ vw,
    unsigned short* __restrict__ hbf, unsigned short* __restrict__ wbf,
    float* __restrict__ aL, float* __restrict__ vArr,
    unsigned int* __restrict__ ctrl) {
  int tid = threadIdx.x;
  int pid = blockIdx.x;
  if (ctrl != nullptr && pid == 0) {
    for (int i = tid; i < 544; i += 256) ctrl[i] = 0u;
  }
  if (pid < 512) {
    int lane = tid & 63, w = tid >> 6;
    int xcd = pid & 7, idx = pid >> 3;
    int row0 = (xcd << 10) + (idx * 4 + w) * 4;
    float4 u4[4], v4[4];
#pragma unroll
    for (int c = 0; c < 4; ++c) {
      u4[c] = *(const float4*)&U[c * 256 + lane * 4];
      v4[c] = *(const float4*)&V[c * 256 + lane * 4];
    }
    float u_t = U[1024], v_t = V[1024];
    float su[4], sv[4];
#pragma unroll
    for (int r = 0; r < 4; ++r) {
      const float* hr = hidden + (size_t)(row0 + r) * 1024;
      unsigned short* hb = hbf + (size_t)(row0 + r) * 1024;
      float ssu = 0.f, ssv = 0.f;
#pragma unroll
      for (int c = 0; c < 4; ++c) {
        float4 x = *(const float4*)&hr[c * 256 + lane * 4];
        ushort4 o;
        o.x = f2bf_u(x.x); o.y = f2bf_u(x.y); o.z = f2bf_u(x.z); o.w = f2bf_u(x.w);
        *(ushort4*)&hb[c * 256 + lane * 4] = o;
        ssu += x.x * u4[c].x + x.y * u4[c].y + x.z * u4[c].z + x.w * u4[c].w;
        ssv += x.x * v4[c].x + x.y * v4[c].y + x.z * v4[c].z + x.w * v4[c].w;
      }
      su[r] = ssu; sv[r] = ssv;
    }
#pragma unroll
    for (int off = 1; off < 64; off <<= 1) {
#pragma unroll
      for (int r = 0; r < 4; ++r) {
        su[r] += __shfl_xor(su[r], off);
        sv[r] += __shfl_xor(sv[r], off);
      }
    }
    if (lane < 4) {
      int r = lane;
      float sur = (r == 0) ? su[0] : (r == 1) ? su[1] : (r == 2) ? su[2] : su[3];
      float svr = (r == 0) ? sv[0] : (r == 1) ? sv[1] : (r == 2) ? sv[2] : sv[3];
      aL[row0 + r] = (sur + u_t) * 0.125f * LOG2E;
      vArr[row0 + r] = svr + v_t;
    }
  } else {
    int wp = pid - 512;  // [0,128)
#pragma unroll
    for (int it = 0; it < 8; ++it) {
      int idx = (wp * 256 + tid) * 4 + it * 131072;
      float4 x = *(const float4*)&vw[idx];
      ushort4 o;
      o.x = f2bf_u(x.x); o.y = f2bf_u(x.y); o.z = f2bf_u(x.z); o.w = f2bf_u(x.w);
      *(ushort4*)&wbf[idx] = o;
    }
  }
}

// ---------------------------------------------------------------------------
// mega: single persistent-ticket kernel replacing gemm_stats + attn.
// 512 blocks x 256 thr, 64KB LDS (2 blocks/CU). Ticket queue (atomic counter
// in ctrl[0]):
//   [0,256)     statsP   (32 rows each, linear; no waits)
//   [256,768)   gemm_vl  (128x128 tile; ticket q: n-tile=q>>6, m-tile=q&63;
//                         no waits — inputs come from the prior launch;
//                         sets flags[q] with agent-scope release)
//   [768,1280)  attn     (ticket a: h-tile=a>>6, i-tile=a&63; waits coarse
//                         stats counter once, then per-K-step on exactly one
//                         producer flag q=(N<<6)|(b<<4)|(k0>>7))
// Deadlock-free for ANY residency: waits only ever target strictly earlier
// tickets, and ticket holders of those never wait. Gemm ticket order is
// m-tile-fastest so attn ticket a depends only on gemm tickets <= (a|15).
// ---------------------------------------------------------------------------
__global__ void __launch_bounds__(256) mega(
    const unsigned short* __restrict__ hbf, const unsigned short* __restrict__ wbf,
    const float* __restrict__ bias, unsigned short* __restrict__ vlt,
    const float* __restrict__ aL, const float* __restrict__ vArr,
    const float* __restrict__ mask, unsigned short* __restrict__ P,
    float* __restrict__ out, unsigned int* __restrict__ ctrl) {
  __shared__ __align__(16) char sA[128 * 256];
  __shared__ __align__(16) char sB[128 * 256];
  __shared__ unsigned int s_t;
  unsigned int* flags = ctrl + 16;
  int tid = threadIdx.x;
  for (;;) {
    __syncthreads();
    if (tid == 0) s_t = atomicAdd(&ctrl[0], 1u);
    __syncthreads();
    unsigned int t = s_t;
    if (t >= 1280u) return;
    if (t < 256u) {
      // ---- statsP: 8 rows/wave, 32 rows/ticket, linear row mapping ----
      int lane = tid & 63, w = tid >> 6;
      int row0 = (int)t * 32 + w * 8;
      int tb = (row0 >> 11) << 11;
      float4 va[8], ma[8];
#pragma unroll
      for (int c = 0; c < 4; ++c) {
        int tt = c * 512 + lane * 8;
        va[2 * c]     = *(const float4*)&vArr[tb + tt];
        va[2 * c + 1] = *(const float4*)&vArr[tb + tt + 4];
        float4 m0v = *(const float4*)&mask[tb + tt];
        float4 m1v = *(const float4*)&mask[tb + tt + 4];
        ma[2 * c].x = m0v.x * LOG2E; ma[2 * c].y = m0v.y * LOG2E;
        ma[2 * c].z = m0v.z * LOG2E; ma[2 * c].w = m0v.w * LOG2E;
        ma[2 * c + 1].x = m1v.x * LOG2E; ma[2 * c + 1].y = m1v.y * LOG2E;
        ma[2 * c + 1].z = m1v.z * LOG2E; ma[2 * c + 1].w = m1v.w * LOG2E;
      }
#pragma unroll
      for (int r = 0; r < 8; ++r) {
        int row = row0 + r;
        float a = aL[row];
        float s[32];
#pragma unroll
        for (int qq = 0; qq < 8; ++qq) {
          s[qq * 4 + 0] = fmaf(a, va[qq].x, ma[qq].x);
          s[qq * 4 + 1] = fmaf(a, va[qq].y, ma[qq].y);
          s[qq * 4 + 2] = fmaf(a, va[qq].z, ma[qq].z);
          s[qq * 4 + 3] = fmaf(a, va[qq].w, ma[qq].w);
        }
        float mx = s[0];
#pragma unroll
        for (int u = 1; u < 32; ++u) mx = fmaxf(mx, s[u]);
#pragma unroll
        for (int off = 1; off < 64; off <<= 1) mx = fmaxf(mx, __shfl_xor(mx, off));
        float z = 0.f;
#pragma unroll
        for (int u = 0; u < 32; ++u) {
          s[u] = __builtin_amdgcn_exp2f(s[u] - mx);
          z += s[u];
        }
#pragma unroll
        for (int off = 1; off < 64; off <<= 1) z += __shfl_xor(z, off);
        float iz = __builtin_amdgcn_rcpf(z);
        unsigned short* pr = P + (size_t)row * 2048;
#pragma unroll
        for (int c = 0; c < 4; ++c) {
          bf16x8 o;
#pragma unroll
          for (int u = 0; u < 8; ++u) o[u] = (__bf16)(iz * s[c * 8 + u]);
          *(bf16x8*)&pr[c * 512 + lane * 8] = o;
        }
      }
      __syncthreads();
      if (tid == 0) {
        __threadfence();
        __hip_atomic_fetch_add(&ctrl[1], 1u, __ATOMIC_RELEASE, __HIP_MEMORY_SCOPE_AGENT);
      }
    } else if (t < 768u) {
      // ---- gemm_vl tile: 128x128, BK=128, 16-chunk XOR swizzle ----
      unsigned int fq = t - 256u;
      int m0 = (int)(fq & 63u) * 128;
      int n0 = (int)(fq >> 6) * 128;
      int lane = tid & 63, wave = tid >> 6;
      int rl = lane >> 4, pc = lane & 15;
      int wr = wave >> 1, wc = wave & 1;
      int m_ = lane & 15, qq = lane >> 4;
      f32x4 acc[4][4] = {};
      for (int k0 = 0; k0 < 1024; k0 += 128) {
        __syncthreads();
#pragma unroll
        for (int ii = 0; ii < 8; ++ii) {
          int rb = wave * 32 + ii * 4;
          int r = rb + rl;
          int gc = pc ^ (r & 15);
          g2lds16(hbf + (size_t)(m0 + r) * 1024 + k0 + gc * 8, sA + rb * 256);
          g2lds16(wbf + (size_t)(n0 + r) * 1024 + k0 + gc * 8, sB + rb * 256);
        }
        __syncthreads();
#pragma unroll
        for (int ks = 0; ks < 4; ++ks) {
          bf16x8 af[4], bfr[4];
#pragma unroll
          for (int i = 0; i < 4; ++i)
            af[i] = *(const bf16x8*)(sA + (wr * 64 + i * 16 + m_) * 256 + (((ks * 4 + qq) ^ m_) * 16));
#pragma unroll
          for (int j = 0; j < 4; ++j)
            bfr[j] = *(const bf16x8*)(sB + (wc * 64 + j * 16 + m_) * 256 + (((ks * 4 + qq) ^ m_) * 16));
#pragma unroll
          for (int i = 0; i < 4; ++i)
#pragma unroll
            for (int j = 0; j < 4; ++j)
              acc[i][j] = __builtin_amdgcn_mfma_f32_16x16x32_bf16(af[i], bfr[j], acc[i][j], 0, 0, 0);
        }
      }
#pragma unroll
      for (int jt = 0; jt < 4; ++jt) {
        int j = n0 + wc * 64 + jt * 16 + m_;
        float bj = bias[j];
#pragma unroll
        for (int it = 0; it < 4; ++it) {
          int i = m0 + wr * 64 + it * 16 + qq * 4;
          f32x4 a = acc[it][jt];
          ushort4 o;
          o.x = f2bf_u(a.x + bj); o.y = f2bf_u(a.y + bj);
          o.z = f2bf_u(a.z + bj); o.w = f2bf_u(a.w + bj);
          *(ushort4*)&vlt[(size_t)j * 8192 + i] = o;
        }
      }
      __syncthreads();
      if (tid == 0) {
        __threadfence();
        __hip_atomic_store(&flags[fq], 1u, __ATOMIC_RELEASE, __HIP_MEMORY_SCOPE_AGENT);
      }
    } else {
      // ---- attn tile: C = P' @ VL^T-slice, K=2048, per-K-step flag wait ----
      unsigned int at = t - 768u;
      int N = (int)(at >> 6), I = (int)(at & 63u);
      int i0 = I * 128, h0 = N * 128;
      int b = I >> 4;
      size_t toff = (size_t)b << 11;
      unsigned int qbase = ((unsigned)N << 6) | ((unsigned)b << 4);
      int lane = tid & 63, wave = tid >> 6;
      int rl = lane >> 4, pc = lane & 15;
      int wr = wave >> 1, wc = wave & 1;
      int m_ = lane & 15, qq = lane >> 4;
      if (tid == 0) {
        while (__hip_atomic_load(&ctrl[1], __ATOMIC_ACQUIRE, __HIP_MEMORY_SCOPE_AGENT) < 256u)
          __builtin_amdgcn_s_sleep(2);
        __threadfence();
      }
      f32x4 acc[4][4] = {};
      for (int k0 = 0; k0 < 2048; k0 += 128) {
        __syncthreads();
        if (tid == 0) {
          unsigned int fq = qbase + (unsigned)(k0 >> 7);
          while (__hip_atomic_load(&flags[fq], __ATOMIC_ACQUIRE, __HIP_MEMORY_SCOPE_AGENT) == 0u)
            __builtin_amdgcn_s_sleep(2);
          __threadfence();
        }
        __syncthreads();
#pragma unroll
        for (int ii = 0; ii < 8; ++ii) {
          int rb = wave * 32 + ii * 4;
          int r = rb + rl;
          int gc = pc ^ (r & 15);
          g2lds16(P + (size_t)(i0 + r) * 2048 + k0 + gc * 8, sA + rb * 256);
          g2lds16(vlt + (size_t)(h0 + r) * 8192 + toff + k0 + gc * 8, sB + rb * 256);
        }
        __syncthreads();
#pragma unroll
        for (int ks = 0; ks < 4; ++ks) {
          bf16x8 af[4], bfr[4];
#pragma unroll
          for (int i = 0; i < 4; ++i)
            af[i] = *(const bf16x8*)(sA + (wr * 64 + i * 16 + m_) * 256 + (((ks * 4 + qq) ^ m_) * 16));
#pragma unroll
          for (int j = 0; j < 4; ++j)
            bfr[j] = *(const bf16x8*)(sB + (wc * 64 + j * 16 + m_) * 256 + (((ks * 4 + qq) ^ m_) * 16));
#pragma unroll
          for (int i = 0; i < 4; ++i)
#pragma unroll
            for (int j = 0; j < 4; ++j)
              acc[i][j] = __builtin_amdgcn_mfma_f32_16x16x32_bf16(af[i], bfr[j], acc[i][j], 0, 0, 0);
        }
      }
#pragma unroll
      for (int it = 0; it < 4; ++it) {
        int gi = i0 + wr * 64 + it * 16 + qq * 4;
#pragma unroll
        for (int jt = 0; jt < 4; ++jt) {
          int h = h0 + wc * 64 + jt * 16 + m_;
          f32x4 a = acc[it][jt];
          out[(size_t)(gi + 0) * 1024 + h] = a.x;
          out[(size_t)(gi + 1) * 1024 + h] = a.y;
          out[(size_t)(gi + 2) * 1024 + h] = a.z;
          out[(size_t)(gi + 3) * 1024 + h] = a.w;
        }
      }
    }
  }
}

// ---------------------------------------------------------------------------
// Fallback kernels (small-ws layout B path) — unchanged from previous round.
// ---------------------------------------------------------------------------
__global__ void __launch_bounds__(256) gemm_stats(
    const unsigned short* __restrict__ hbf, const unsigned short* __restrict__ wbf,
    const float* __restrict__ bias, unsigned short* __restrict__ vlt,
    const float* __restrict__ aL, const float* __restrict__ vArr,
    const float* __restrict__ mask, unsigned short* __restrict__ P,
    int statsBlocks) {
  __shared__ __align__(16) char sA[128 * 256];
  __shared__ __align__(16) char sB[128 * 256];
  int tid = threadIdx.x;
  int pid = blockIdx.x;
  if (pid >= statsBlocks) {
    int g = pid - statsBlocks;
    int lane = tid & 63, wave = tid >> 6;
    int xcd = g & 7, kk = g >> 3;
    int m0 = (xcd * 8 + (kk >> 3)) * 128;
    int n0 = (kk & 7) * 128;
    int rl = lane >> 4, pc = lane & 15;
    int wr = wave >> 1, wc = wave & 1;
    int m_ = lane & 15, q = lane >> 4;
    f32x4 acc[4][4] = {};
    for (int k0 = 0; k0 < 1024; k0 += 128) {
      __syncthreads();
#pragma unroll
      for (int ii = 0; ii < 8; ++ii) {
        int rb = wave * 32 + ii * 4;
        int r = rb + rl;
        int gc = pc ^ (r & 15);
        g2lds16(hbf + (size_t)(m0 + r) * 1024 + k0 + gc * 8, sA + rb * 256);
        g2lds16(wbf + (size_t)(n0 + r) * 1024 + k0 + gc * 8, sB + rb * 256);
      }
      __syncthreads();
#pragma unroll
      for (int ks = 0; ks < 4; ++ks) {
        bf16x8 af[4], bfr[4];
#pragma unroll
        for (int i = 0; i < 4; ++i)
          af[i] = *(const bf16x8*)(sA + (wr * 64 + i * 16 + m_) * 256 + (((ks * 4 + q) ^ m_) * 16));
#pragma unroll
        for (int j = 0; j < 4; ++j)
          bfr[j] = *(const bf16x8*)(sB + (wc * 64 + j * 16 + m_) * 256 + (((ks * 4 + q) ^ m_) * 16));
#pragma unroll
        for (int i = 0; i < 4; ++i)
#pragma unroll
          for (int j = 0; j < 4; ++j)
            acc[i][j] = __builtin_amdgcn_mfma_f32_16x16x32_bf16(af[i], bfr[j], acc[i][j], 0, 0, 0);
      }
    }
#pragma unroll
    for (int jt = 0; jt < 4; ++jt) {
      int j = n0 + wc * 64 + jt * 16 + m_;
      float bj = bias[j];
#pragma unroll
      for (int it = 0; it < 4; ++it) {
        int i = m0 + wr * 64 + it * 16 + q * 4;
        f32x4 a = acc[it][jt];
        ushort4 o;
        o.x = f2bf_u(a.x + bj); o.y = f2bf_u(a.y + bj);
        o.z = f2bf_u(a.z + bj); o.w = f2bf_u(a.w + bj);
        *(ushort4*)&vlt[(size_t)j * 8192 + i] = o;
      }
    }
  } else {
    int b = pid;
    int lane = tid & 63, w = tid >> 6;
    int xcd = b & 7, idx = b >> 3;
    int row0 = (xcd << 10) + (idx * 4 + w) * 8;
    int tb = (row0 >> 11) << 11;
    float4 va[8], ma[8];
#pragma unroll
    for (int c = 0; c < 4; ++c) {
      int t = c * 512 + lane * 8;
      va[2 * c]     = *(const float4*)&vArr[tb + t];
      va[2 * c + 1] = *(const float4*)&vArr[tb + t + 4];
      float4 m0v = *(const float4*)&mask[tb + t];
      float4 m1v = *(const float4*)&mask[tb + t + 4];
      ma[2 * c].x = m0v.x * LOG2E; ma[2 * c].y = m0v.y * LOG2E;
      ma[2 * c].z = m0v.z * LOG2E; ma[2 * c].w = m0v.w * LOG2E;
      ma[2 * c + 1].x = m1v.x * LOG2E; ma[2 * c + 1].y = m1v.y * LOG2E;
      ma[2 * c + 1].z = m1v.z * LOG2E; ma[2 * c + 1].w = m1v.w * LOG2E;
    }
#pragma unroll
    for (int r = 0; r < 8; ++r) {
      int row = row0 + r;
      float a = aL[row];
      float s[32];
#pragma unroll
      for (int qq = 0; qq < 8; ++qq) {
        s[qq * 4 + 0] = fmaf(a, va[qq].x, ma[qq].x);
        s[qq * 4 + 1] = fmaf(a, va[qq].y, ma[qq].y);
        s[qq * 4 + 2] = fmaf(a, va[qq].z, ma[qq].z);
        s[qq * 4 + 3] = fmaf(a, va[qq].w, ma[qq].w);
      }
      float mx = s[0];
#pragma unroll
      for (int u = 1; u < 32; ++u) mx = fmaxf(mx, s[u]);
#pragma unroll
      for (int off = 1; off < 64; off <<= 1) mx = fmaxf(mx, __shfl_xor(mx, off));
      float z = 0.f;
#pragma unroll
      for (int u = 0; u < 32; ++u) {
        s[u] = __builtin_amdgcn_exp2f(s[u] - mx);
        z += s[u];
      }
#pragma unroll
      for (int off = 1; off < 64; off <<= 1) z += __shfl_xor(z, off);
      float iz = __builtin_amdgcn_rcpf(z);
      unsigned short* pr = P + (size_t)row * 2048;
#pragma unroll
      for (int c = 0; c < 4; ++c) {
        bf16x8 o;
#pragma unroll
        for (int u = 0; u < 8; ++u) o[u] = (__bf16)(iz * s[c * 8 + u]);
        *(bf16x8*)&pr[c * 512 + lane * 8] = o;
      }
    }
  }
}

__global__ void __launch_bounds__(256) attn(
    const unsigned short* __restrict__ p, const unsigned short* __restrict__ vlt,
    float* __restrict__ out) {
  __shared__ __align__(16) char sA[128 * 256];
  __shared__ __align__(16) char sB[128 * 256];
  int tid = threadIdx.x;
  int lane = tid & 63, wave = tid >> 6;
  int pid = blockIdx.x;
  int xcd = pid & 7, kk = pid >> 3;
  int i0 = (xcd * 8 + (kk >> 3)) * 128;
  int h0 = (kk & 7) * 128;
  int b = i0 >> 11;
  size_t toff = (size_t)b << 11;
  int rl = lane >> 4, pc = lane & 15;
  int wr = wave >> 1, wc = wave & 1;
  int m_ = lane & 15, q = lane >> 4;
  f32x4 acc[4][4] = {};
  for (int k0 = 0; k0 < 2048; k0 += 128) {
    __syncthreads();
#pragma unroll
    for (int ii = 0; ii < 8; ++ii) {
      int rb = wave * 32 + ii * 4;
      int r = rb + rl;
      int gc = pc ^ (r & 15);
      g2lds16(p + (size_t)(i0 + r) * 2048 + k0 + gc * 8, sA + rb * 256);
      g2lds16(vlt + (size_t)(h0 + r) * 8192 + toff + k0 + gc * 8, sB + rb * 256);
    }
    __syncthreads();
#pragma unroll
    for (int ks = 0; ks < 4; ++ks) {
      bf16x8 af[4], bfr[4];
#pragma unroll
      for (int i = 0; i < 4; ++i)
        af[i] = *(const bf16x8*)(sA + (wr * 64 + i * 16 + m_) * 256 + (((ks * 4 + q) ^ m_) * 16));
#pragma unroll
      for (int j = 0; j < 4; ++j)
        bfr[j] = *(const bf16x8*)(sB + (wc * 64 + j * 16 + m_) * 256 + (((ks * 4 + q) ^ m_) * 16));
#pragma unroll
      for (int i = 0; i < 4; ++i)
#pragma unroll
        for (int j = 0; j < 4; ++j)
          acc[i][j] = __builtin_amdgcn_mfma_f32_16x16x32_bf16(af[i], bfr[j], acc[i][j], 0, 0, 0);
    }
  }
#pragma unroll
  for (int it = 0; it < 4; ++it) {
    int gi = i0 + wr * 64 + it * 16 + q * 4;
#pragma unroll
    for (int jt = 0; jt < 4; ++jt) {
      int h = h0 + wc * 64 + jt * 16 + m_;
      f32x4 a = acc[it][jt];
      out[(size_t)(gi + 0) * 1024 + h] = a.x;
      out[(size_t)(gi + 1) * 1024 + h] = a.y;
      out[(size_t)(gi + 2) * 1024 + h] = a.z;
      out[(size_t)(gi + 3) * 1024 + h] = a.w;
    }
  }
}

// ---------------------------------------------------------------------------
// Layout A (ws >= 69.28 MB, 2 launches — prep then persistent mega):
//   hbf 0..16MB | wbf 16..18MB | vlt 18..34.8MB | P 34.8..68.3MB | aL,vArr |
//   ctrl (ticket counter + stats counter + 512 gemm flags) at 69271552.
// Layout B (fallback, 4 launches; P overlaps dead hbf/wbf).
// ---------------------------------------------------------------------------
extern "C" void kernel_launch(void* const* d_in, const int* in_sizes, int n_in,
                              void* d_out, int out_size, void* d_ws, size_t ws_size,
                              hipStream_t stream) {
  const float* hidden = (const float*)d_in[0];
  const float* mask   = (const float*)d_in[1];
  const float* vw     = (const float*)d_in[2];
  const float* vb     = (const float*)d_in[3];
  const float* U      = (const float*)d_in[4];
  const float* V      = (const float*)d_in[5];
  float* out = (float*)d_out;
  char* ws = (char*)d_ws;

  if (ws_size >= 69275648ull) {
    unsigned short* hbf = (unsigned short*)ws;
    unsigned short* wbf = (unsigned short*)(ws + 16777216);
    unsigned short* vlt = (unsigned short*)(ws + 18874368);
    unsigned short* P   = (unsigned short*)(ws + 35651584);
    float* aL   = (float*)(ws + 69206016);
    float* vArr = aL + 8192;
    unsigned int* ctrl = (unsigned int*)(ws + 69271552);
    fused_prep<<<640, 256, 0, stream>>>(hidden, U, V, vw, hbf, wbf, aL, vArr, ctrl);
    mega<<<512, 256, 0, stream>>>(hbf, wbf, vb, vlt, aL, vArr, mask, P, out, ctrl);
  } else {
    unsigned short* hbf = (unsigned short*)ws;
    unsigned short* wbf = (unsigned short*)(ws + 16777216);
    unsigned short* P   = (unsigned short*)ws;               // overlaps dead hbf/wbf
    unsigned short* vlt = (unsigned short*)(ws + 33554432);
    float* aL   = (float*)(ws + 50331648);
    float* vArr = aL + 8192;
    fused_prep<<<640, 256, 0, stream>>>(hidden, U, V, vw, hbf, wbf, aL, vArr, nullptr);
    gemm_stats<<<512, 256, 0, stream>>>(hbf, wbf, vb, vlt, aL, vArr, mask, P, 0);
    gemm_stats<<<256, 256, 0, stream>>>(hbf, wbf, vb, vlt, aL, vArr, mask, P, 256);
    attn<<<512, 256, 0, stream>>>(P, vlt, out);
  }
}

// Round 3
// 204.307 us; speedup vs baseline: 2.6910x; 2.6910x over previous
//
#include <hip/hip_runtime.h>
#include <hip/hip_bf16.h>
#include <stdint.h>

#define LOG2E 1.44269504088896340736f

typedef float f32x4 __attribute__((ext_vector_type(4)));
typedef __bf16 bf16x8 __attribute__((ext_vector_type(8)));

__device__ __forceinline__ void g2lds16(const void* g, void* l) {
  __builtin_amdgcn_global_load_lds(
      (__attribute__((address_space(1))) unsigned int*)g,
      (__attribute__((address_space(3))) unsigned int*)l,
      16, 0, 0);
}

__device__ __forceinline__ unsigned short f2bf_u(float f) {
  __bf16 h = (__bf16)f;
  return __builtin_bit_cast(unsigned short, h);
}

// Grid barrier (plain launch, de-facto co-residency: 512 blocks, 64KB LDS,
// __launch_bounds__(256,2) => 2 blocks/CU * 256 CU = 512, stream empty at
// launch so all blocks dispatch immediately).
// Round-1 lesson: agent-scope ACQUIRE in a spin loop invalidates the XCD L2
// every poll -> cache catastrophe. Here: ONE release add per block (flushes
// its dirty L2 lines, needed anyway), RELAXED polling (goes to coherence
// point, no cache side effects), then ONE acquire fence per block.
__device__ __forceinline__ void grid_barrier(unsigned int* cnt, int tid,
                                             unsigned int nb) {
  __syncthreads();
  if (tid == 0) {
    __hip_atomic_fetch_add(cnt, 1u, __ATOMIC_RELEASE, __HIP_MEMORY_SCOPE_AGENT);
    while (__hip_atomic_load(cnt, __ATOMIC_RELAXED, __HIP_MEMORY_SCOPE_AGENT) < nb)
      __builtin_amdgcn_s_sleep(2);
    __builtin_amdgcn_fence(__ATOMIC_ACQUIRE, "agent");
  }
  __syncthreads();
}

// ---------------------------------------------------------------------------
// fused_prep: 640 blocks (round-0 proven). pid<512: hidden prep. pid>=512:
// vw bf16 cast. Block 0 additionally zeroes the 16-word ctrl block; the
// kernel boundary makes it visible to mega2.
// ---------------------------------------------------------------------------
__global__ void __launch_bounds__(256) fused_prep(
    const float* __restrict__ hidden, const float* __restrict__ U,
    const float* __restrict__ V, const float* __restrict__ vw,
    unsigned short* __restrict__ hbf, unsigned short* __restrict__ wbf,
    float* __restrict__ aL, float* __restrict__ vArr,
    unsigned int* __restrict__ ctrl) {
  int tid = threadIdx.x;
  int pid = blockIdx.x;
  if (ctrl != nullptr && pid == 0 && tid < 16) ctrl[tid] = 0u;
  if (pid < 512) {
    int lane = tid & 63, w = tid >> 6;
    int xcd = pid & 7, idx = pid >> 3;
    int row0 = (xcd << 10) + (idx * 4 + w) * 4;
    float4 u4[4], v4[4];
#pragma unroll
    for (int c = 0; c < 4; ++c) {
      u4[c] = *(const float4*)&U[c * 256 + lane * 4];
      v4[c] = *(const float4*)&V[c * 256 + lane * 4];
    }
    float u_t = U[1024], v_t = V[1024];
    float su[4], sv[4];
#pragma unroll
    for (int r = 0; r < 4; ++r) {
      const float* hr = hidden + (size_t)(row0 + r) * 1024;
      unsigned short* hb = hbf + (size_t)(row0 + r) * 1024;
      float ssu = 0.f, ssv = 0.f;
#pragma unroll
      for (int c = 0; c < 4; ++c) {
        float4 x = *(const float4*)&hr[c * 256 + lane * 4];
        ushort4 o;
        o.x = f2bf_u(x.x); o.y = f2bf_u(x.y); o.z = f2bf_u(x.z); o.w = f2bf_u(x.w);
        *(ushort4*)&hb[c * 256 + lane * 4] = o;
        ssu += x.x * u4[c].x + x.y * u4[c].y + x.z * u4[c].z + x.w * u4[c].w;
        ssv += x.x * v4[c].x + x.y * v4[c].y + x.z * v4[c].z + x.w * v4[c].w;
      }
      su[r] = ssu; sv[r] = ssv;
    }
#pragma unroll
    for (int off = 1; off < 64; off <<= 1) {
#pragma unroll
      for (int r = 0; r < 4; ++r) {
        su[r] += __shfl_xor(su[r], off);
        sv[r] += __shfl_xor(sv[r], off);
      }
    }
    if (lane < 4) {
      int r = lane;
      float sur = (r == 0) ? su[0] : (r == 1) ? su[1] : (r == 2) ? su[2] : su[3];
      float svr = (r == 0) ? sv[0] : (r == 1) ? sv[1] : (r == 2) ? sv[2] : sv[3];
      aL[row0 + r] = (sur + u_t) * 0.125f * LOG2E;
      vArr[row0 + r] = svr + v_t;
    }
  } else {
    int wp = pid - 512;
#pragma unroll
    for (int it = 0; it < 8; ++it) {
      int idx = (wp * 256 + tid) * 4 + it * 131072;
      float4 x = *(const float4*)&vw[idx];
      ushort4 o;
      o.x = f2bf_u(x.x); o.y = f2bf_u(x.y); o.z = f2bf_u(x.z); o.w = f2bf_u(x.w);
      *(ushort4*)&wbf[idx] = o;
    }
  }
}

// ---------------------------------------------------------------------------
// mega2: plain-launched 512 blocks x 256 thr, 64KB LDS, launch_bounds(256,2)
// guarantees 2 blocks/CU residency capability. Grid-stride over 512 work
// units per phase (1 unit/block at the intended grid).
//   phase 1a: softmax stats (16 P-rows/unit)     [round-0 statsP body]
//   phase 1b: gemm_vl tile (128x128, BK=128)      [round-0 gemm body]
//   grid barrier (visibility: vlt, P)
//   phase 2:  attn tile (128x128, K=2048)         [round-0 attn body]
// ---------------------------------------------------------------------------
__global__ void __launch_bounds__(256, 2) mega2(
    const unsigned short* __restrict__ hbf, const unsigned short* __restrict__ wbf,
    const float* __restrict__ bias, unsigned short* __restrict__ vlt,
    const float* __restrict__ aL, const float* __restrict__ vArr,
    const float* __restrict__ mask, unsigned short* __restrict__ P,
    float* __restrict__ out, unsigned int* __restrict__ ctrl) {
  __shared__ __align__(16) char sA[128 * 256];
  __shared__ __align__(16) char sB[128 * 256];
  int tid = threadIdx.x;
  int bid = blockIdx.x;
  unsigned int nb = gridDim.x;
  int lane = tid & 63, wave = tid >> 6;

  // ---- phase 1a: softmax stats -> P (16 rows/unit, 4 rows/wave) ----
  for (int u = bid; u < 512; u += (int)nb) {
    int row0 = u * 16 + wave * 4;
    int tb = (row0 >> 11) << 11;  // batch base; block's rows never straddle
    float4 va[8], ma[8];
#pragma unroll
    for (int c = 0; c < 4; ++c) {
      int tt = c * 512 + lane * 8;
      va[2 * c]     = *(const float4*)&vArr[tb + tt];
      va[2 * c + 1] = *(const float4*)&vArr[tb + tt + 4];
      float4 m0v = *(const float4*)&mask[tb + tt];
      float4 m1v = *(const float4*)&mask[tb + tt + 4];
      ma[2 * c].x = m0v.x * LOG2E; ma[2 * c].y = m0v.y * LOG2E;
      ma[2 * c].z = m0v.z * LOG2E; ma[2 * c].w = m0v.w * LOG2E;
      ma[2 * c + 1].x = m1v.x * LOG2E; ma[2 * c + 1].y = m1v.y * LOG2E;
      ma[2 * c + 1].z = m1v.z * LOG2E; ma[2 * c + 1].w = m1v.w * LOG2E;
    }
#pragma unroll
    for (int r = 0; r < 4; ++r) {
      int row = row0 + r;
      float a = aL[row];
      float s[32];
#pragma unroll
      for (int qq = 0; qq < 8; ++qq) {
        s[qq * 4 + 0] = fmaf(a, va[qq].x, ma[qq].x);
        s[qq * 4 + 1] = fmaf(a, va[qq].y, ma[qq].y);
        s[qq * 4 + 2] = fmaf(a, va[qq].z, ma[qq].z);
        s[qq * 4 + 3] = fmaf(a, va[qq].w, ma[qq].w);
      }
      float mx = s[0];
#pragma unroll
      for (int uu = 1; uu < 32; ++uu) mx = fmaxf(mx, s[uu]);
#pragma unroll
      for (int off = 1; off < 64; off <<= 1) mx = fmaxf(mx, __shfl_xor(mx, off));
      float z = 0.f;
#pragma unroll
      for (int uu = 0; uu < 32; ++uu) {
        s[uu] = __builtin_amdgcn_exp2f(s[uu] - mx);
        z += s[uu];
      }
#pragma unroll
      for (int off = 1; off < 64; off <<= 1) z += __shfl_xor(z, off);
      float iz = __builtin_amdgcn_rcpf(z);
      unsigned short* pr = P + (size_t)row * 2048;
#pragma unroll
      for (int c = 0; c < 4; ++c) {
        bf16x8 o;
#pragma unroll
        for (int uu = 0; uu < 8; ++uu) o[uu] = (__bf16)(iz * s[c * 8 + uu]);
        *(bf16x8*)&pr[c * 512 + lane * 8] = o;
      }
    }
  }

  // ---- phase 1b: gemm_vl tile: 128x128, BK=128, 16-chunk XOR swizzle ----
  for (int u = bid; u < 512; u += (int)nb) {
    int xcd = u & 7, kk = u >> 3;
    int m0 = (xcd * 8 + (kk >> 3)) * 128;
    int n0 = (kk & 7) * 128;
    int rl = lane >> 4, pc = lane & 15;
    int wr = wave >> 1, wc = wave & 1;
    int m_ = lane & 15, qq = lane >> 4;
    f32x4 acc[4][4] = {};
    for (int k0 = 0; k0 < 1024; k0 += 128) {
      __syncthreads();
#pragma unroll
      for (int ii = 0; ii < 8; ++ii) {
        int rb = wave * 32 + ii * 4;
        int r = rb + rl;
        int gc = pc ^ (r & 15);
        g2lds16(hbf + (size_t)(m0 + r) * 1024 + k0 + gc * 8, sA + rb * 256);
        g2lds16(wbf + (size_t)(n0 + r) * 1024 + k0 + gc * 8, sB + rb * 256);
      }
      __syncthreads();
#pragma unroll
      for (int ks = 0; ks < 4; ++ks) {
        bf16x8 af[4], bfr[4];
#pragma unroll
        for (int i = 0; i < 4; ++i)
          af[i] = *(const bf16x8*)(sA + (wr * 64 + i * 16 + m_) * 256 + (((ks * 4 + qq) ^ m_) * 16));
#pragma unroll
        for (int j = 0; j < 4; ++j)
          bfr[j] = *(const bf16x8*)(sB + (wc * 64 + j * 16 + m_) * 256 + (((ks * 4 + qq) ^ m_) * 16));
#pragma unroll
        for (int i = 0; i < 4; ++i)
#pragma unroll
          for (int j = 0; j < 4; ++j)
            acc[i][j] = __builtin_amdgcn_mfma_f32_16x16x32_bf16(af[i], bfr[j], acc[i][j], 0, 0, 0);
      }
    }
#pragma unroll
    for (int jt = 0; jt < 4; ++jt) {
      int j = n0 + wc * 64 + jt * 16 + m_;
      float bj = bias[j];
#pragma unroll
      for (int it = 0; it < 4; ++it) {
        int i = m0 + wr * 64 + it * 16 + qq * 4;
        f32x4 a = acc[it][jt];
        ushort4 o;
        o.x = f2bf_u(a.x + bj); o.y = f2bf_u(a.y + bj);
        o.z = f2bf_u(a.z + bj); o.w = f2bf_u(a.w + bj);
        *(ushort4*)&vlt[(size_t)j * 8192 + i] = o;
      }
    }
  }

  grid_barrier(&ctrl[0], tid, nb);

  // ---- phase 2: attn tile: C = P' @ VL^T-slice, K=2048, BK=128 ----
  for (int u = bid; u < 512; u += (int)nb) {
    int xcd = u & 7, kk = u >> 3;
    int i0 = (xcd * 8 + (kk >> 3)) * 128;
    int h0 = (kk & 7) * 128;
    int b = i0 >> 11;
    size_t toff = (size_t)b << 11;
    int rl = lane >> 4, pc = lane & 15;
    int wr = wave >> 1, wc = wave & 1;
    int m_ = lane & 15, qq = lane >> 4;
    f32x4 acc[4][4] = {};
    for (int k0 = 0; k0 < 2048; k0 += 128) {
      __syncthreads();
#pragma unroll
      for (int ii = 0; ii < 8; ++ii) {
        int rb = wave * 32 + ii * 4;
        int r = rb + rl;
        int gc = pc ^ (r & 15);
        g2lds16(P + (size_t)(i0 + r) * 2048 + k0 + gc * 8, sA + rb * 256);
        g2lds16(vlt + (size_t)(h0 + r) * 8192 + toff + k0 + gc * 8, sB + rb * 256);
      }
      __syncthreads();
#pragma unroll
      for (int ks = 0; ks < 4; ++ks) {
        bf16x8 af[4], bfr[4];
#pragma unroll
        for (int i = 0; i < 4; ++i)
          af[i] = *(const bf16x8*)(sA + (wr * 64 + i * 16 + m_) * 256 + (((ks * 4 + qq) ^ m_) * 16));
#pragma unroll
        for (int j = 0; j < 4; ++j)
          bfr[j] = *(const bf16x8*)(sB + (wc * 64 + j * 16 + m_) * 256 + (((ks * 4 + qq) ^ m_) * 16));
#pragma unroll
        for (int i = 0; i < 4; ++i)
#pragma unroll
          for (int j = 0; j < 4; ++j)
            acc[i][j] = __builtin_amdgcn_mfma_f32_16x16x32_bf16(af[i], bfr[j], acc[i][j], 0, 0, 0);
      }
    }
#pragma unroll
    for (int it = 0; it < 4; ++it) {
      int gi = i0 + wr * 64 + it * 16 + qq * 4;
#pragma unroll
      for (int jt = 0; jt < 4; ++jt) {
        int h = h0 + wc * 64 + jt * 16 + m_;
        f32x4 a = acc[it][jt];
        out[(size_t)(gi + 0) * 1024 + h] = a.x;
        out[(size_t)(gi + 1) * 1024 + h] = a.y;
        out[(size_t)(gi + 2) * 1024 + h] = a.z;
        out[(size_t)(gi + 3) * 1024 + h] = a.w;
      }
    }
  }
}

// ---------------------------------------------------------------------------
// Fallback kernels (small-ws layout B) — round-0 proven code.
// ---------------------------------------------------------------------------
__global__ void __launch_bounds__(256) gemm_stats(
    const unsigned short* __restrict__ hbf, const unsigned short* __restrict__ wbf,
    const float* __restrict__ bias, unsigned short* __restrict__ vlt,
    const float* __restrict__ aL, const float* __restrict__ vArr,
    const float* __restrict__ mask, unsigned short* __restrict__ P,
    int statsBlocks) {
  __shared__ __align__(16) char sA[128 * 256];
  __shared__ __align__(16) char sB[128 * 256];
  int tid = threadIdx.x;
  int pid = blockIdx.x;
  if (pid >= statsBlocks) {
    int g = pid - statsBlocks;
    int lane = tid & 63, wave = tid >> 6;
    int xcd = g & 7, kk = g >> 3;
    int m0 = (xcd * 8 + (kk >> 3)) * 128;
    int n0 = (kk & 7) * 128;
    int rl = lane >> 4, pc = lane & 15;
    int wr = wave >> 1, wc = wave & 1;
    int m_ = lane & 15, q = lane >> 4;
    f32x4 acc[4][4] = {};
    for (int k0 = 0; k0 < 1024; k0 += 128) {
      __syncthreads();
#pragma unroll
      for (int ii = 0; ii < 8; ++ii) {
        int rb = wave * 32 + ii * 4;
        int r = rb + rl;
        int gc = pc ^ (r & 15);
        g2lds16(hbf + (size_t)(m0 + r) * 1024 + k0 + gc * 8, sA + rb * 256);
        g2lds16(wbf + (size_t)(n0 + r) * 1024 + k0 + gc * 8, sB + rb * 256);
      }
      __syncthreads();
#pragma unroll
      for (int ks = 0; ks < 4; ++ks) {
        bf16x8 af[4], bfr[4];
#pragma unroll
        for (int i = 0; i < 4; ++i)
          af[i] = *(const bf16x8*)(sA + (wr * 64 + i * 16 + m_) * 256 + (((ks * 4 + q) ^ m_) * 16));
#pragma unroll
        for (int j = 0; j < 4; ++j)
          bfr[j] = *(const bf16x8*)(sB + (wc * 64 + j * 16 + m_) * 256 + (((ks * 4 + q) ^ m_) * 16));
#pragma unroll
        for (int i = 0; i < 4; ++i)
#pragma unroll
          for (int j = 0; j < 4; ++j)
            acc[i][j] = __builtin_amdgcn_mfma_f32_16x16x32_bf16(af[i], bfr[j], acc[i][j], 0, 0, 0);
      }
    }
#pragma unroll
    for (int jt = 0; jt < 4; ++jt) {
      int j = n0 + wc * 64 + jt * 16 + m_;
      float bj = bias[j];
#pragma unroll
      for (int it = 0; it < 4; ++it) {
        int i = m0 + wr * 64 + it * 16 + q * 4;
        f32x4 a = acc[it][jt];
        ushort4 o;
        o.x = f2bf_u(a.x + bj); o.y = f2bf_u(a.y + bj);
        o.z = f2bf_u(a.z + bj); o.w = f2bf_u(a.w + bj);
        *(ushort4*)&vlt[(size_t)j * 8192 + i] = o;
      }
    }
  } else {
    int b = pid;
    int lane = tid & 63, w = tid >> 6;
    int xcd = b & 7, idx = b >> 3;
    int row0 = (xcd << 10) + (idx * 4 + w) * 8;
    int tb = (row0 >> 11) << 11;
    float4 va[8], ma[8];
#pragma unroll
    for (int c = 0; c < 4; ++c) {
      int t = c * 512 + lane * 8;
      va[2 * c]     = *(const float4*)&vArr[tb + t];
      va[2 * c + 1] = *(const float4*)&vArr[tb + t + 4];
      float4 m0v = *(const float4*)&mask[tb + t];
      float4 m1v = *(const float4*)&mask[tb + t + 4];
      ma[2 * c].x = m0v.x * LOG2E; ma[2 * c].y = m0v.y * LOG2E;
      ma[2 * c].z = m0v.z * LOG2E; ma[2 * c].w = m0v.w * LOG2E;
      ma[2 * c + 1].x = m1v.x * LOG2E; ma[2 * c + 1].y = m1v.y * LOG2E;
      ma[2 * c + 1].z = m1v.z * LOG2E; ma[2 * c + 1].w = m1v.w * LOG2E;
    }
#pragma unroll
    for (int r = 0; r < 8; ++r) {
      int row = row0 + r;
      float a = aL[row];
      float s[32];
#pragma unroll
      for (int qq = 0; qq < 8; ++qq) {
        s[qq * 4 + 0] = fmaf(a, va[qq].x, ma[qq].x);
        s[qq * 4 + 1] = fmaf(a, va[qq].y, ma[qq].y);
        s[qq * 4 + 2] = fmaf(a, va[qq].z, ma[qq].z);
        s[qq * 4 + 3] = fmaf(a, va[qq].w, ma[qq].w);
      }
      float mx = s[0];
#pragma unroll
      for (int u = 1; u < 32; ++u) mx = fmaxf(mx, s[u]);
#pragma unroll
      for (int off = 1; off < 64; off <<= 1) mx = fmaxf(mx, __shfl_xor(mx, off));
      float z = 0.f;
#pragma unroll
      for (int u = 0; u < 32; ++u) {
        s[u] = __builtin_amdgcn_exp2f(s[u] - mx);
        z += s[u];
      }
#pragma unroll
      for (int off = 1; off < 64; off <<= 1) z += __shfl_xor(z, off);
      float iz = __builtin_amdgcn_rcpf(z);
      unsigned short* pr = P + (size_t)row * 2048;
#pragma unroll
      for (int c = 0; c < 4; ++c) {
        bf16x8 o;
#pragma unroll
        for (int u = 0; u < 8; ++u) o[u] = (__bf16)(iz * s[c * 8 + u]);
        *(bf16x8*)&pr[c * 512 + lane * 8] = o;
      }
    }
  }
}

__global__ void __launch_bounds__(256) attn(
    const unsigned short* __restrict__ p, const unsigned short* __restrict__ vlt,
    float* __restrict__ out) {
  __shared__ __align__(16) char sA[128 * 256];
  __shared__ __align__(16) char sB[128 * 256];
  int tid = threadIdx.x;
  int lane = tid & 63, wave = tid >> 6;
  int pid = blockIdx.x;
  int xcd = pid & 7, kk = pid >> 3;
  int i0 = (xcd * 8 + (kk >> 3)) * 128;
  int h0 = (kk & 7) * 128;
  int b = i0 >> 11;
  size_t toff = (size_t)b << 11;
  int rl = lane >> 4, pc = lane & 15;
  int wr = wave >> 1, wc = wave & 1;
  int m_ = lane & 15, q = lane >> 4;
  f32x4 acc[4][4] = {};
  for (int k0 = 0; k0 < 2048; k0 += 128) {
    __syncthreads();
#pragma unroll
    for (int ii = 0; ii < 8; ++ii) {
      int rb = wave * 32 + ii * 4;
      int r = rb + rl;
      int gc = pc ^ (r & 15);
      g2lds16(p + (size_t)(i0 + r) * 2048 + k0 + gc * 8, sA + rb * 256);
      g2lds16(vlt + (size_t)(h0 + r) * 8192 + toff + k0 + gc * 8, sB + rb * 256);
    }
    __syncthreads();
#pragma unroll
    for (int ks = 0; ks < 4; ++ks) {
      bf16x8 af[4], bfr[4];
#pragma unroll
      for (int i = 0; i < 4; ++i)
        af[i] = *(const bf16x8*)(sA + (wr * 64 + i * 16 + m_) * 256 + (((ks * 4 + q) ^ m_) * 16));
#pragma unroll
      for (int j = 0; j < 4; ++j)
        bfr[j] = *(const bf16x8*)(sB + (wc * 64 + j * 16 + m_) * 256 + (((ks * 4 + q) ^ m_) * 16));
#pragma unroll
      for (int i = 0; i < 4; ++i)
#pragma unroll
        for (int j = 0; j < 4; ++j)
          acc[i][j] = __builtin_amdgcn_mfma_f32_16x16x32_bf16(af[i], bfr[j], acc[i][j], 0, 0, 0);
    }
  }
#pragma unroll
  for (int it = 0; it < 4; ++it) {
    int gi = i0 + wr * 64 + it * 16 + q * 4;
#pragma unroll
    for (int jt = 0; jt < 4; ++jt) {
      int h = h0 + wc * 64 + jt * 16 + m_;
      f32x4 a = acc[it][jt];
      out[(size_t)(gi + 0) * 1024 + h] = a.x;
      out[(size_t)(gi + 1) * 1024 + h] = a.y;
      out[(size_t)(gi + 2) * 1024 + h] = a.z;
      out[(size_t)(gi + 3) * 1024 + h] = a.w;
    }
  }
}

// ---------------------------------------------------------------------------
// Layout A (ws >= 69.28 MB, 2 plain launches — prep zeroes ctrl, then mega2
// with in-kernel grid barrier):
//   hbf 0..16MB | wbf 16..18MB | vlt 18..34.8MB | P 34.8..68.3MB | aL,vArr |
//   ctrl (16 words) at 69271552.
// Layout B (fallback, 4 launches; P overlaps dead hbf/wbf).
// ---------------------------------------------------------------------------
extern "C" void kernel_launch(void* const* d_in, const int* in_sizes, int n_in,
                              void* d_out, int out_size, void* d_ws, size_t ws_size,
                              hipStream_t stream) {
  const float* hidden = (const float*)d_in[0];
  const float* mask   = (const float*)d_in[1];
  const float* vw     = (const float*)d_in[2];
  const float* vb     = (const float*)d_in[3];
  const float* U      = (const float*)d_in[4];
  const float* V      = (const float*)d_in[5];
  float* out = (float*)d_out;
  char* ws = (char*)d_ws;

  if (ws_size >= 69275648ull) {
    unsigned short* hbf = (unsigned short*)ws;
    unsigned short* wbf = (unsigned short*)(ws + 16777216);
    unsigned short* vlt = (unsigned short*)(ws + 18874368);
    unsigned short* P   = (unsigned short*)(ws + 35651584);
    float* aL   = (float*)(ws + 69206016);
    float* vArr = aL + 8192;
    unsigned int* ctrl = (unsigned int*)(ws + 69271552);
    fused_prep<<<640, 256, 0, stream>>>(hidden, U, V, vw, hbf, wbf, aL, vArr, ctrl);
    mega2<<<512, 256, 0, stream>>>(hbf, wbf, vb, vlt, aL, vArr, mask, P, out, ctrl);
  } else {
    unsigned short* hbf = (unsigned short*)ws;
    unsigned short* wbf = (unsigned short*)(ws + 16777216);
    unsigned short* P   = (unsigned short*)ws;               // overlaps dead hbf/wbf
    unsigned short* vlt = (unsigned short*)(ws + 33554432);
    float* aL   = (float*)(ws + 50331648);
    float* vArr = aL + 8192;
    fused_prep<<<640, 256, 0, stream>>>(hidden, U, V, vw, hbf, wbf, aL, vArr, nullptr);
    gemm_stats<<<512, 256, 0, stream>>>(hbf, wbf, vb, vlt, aL, vArr, mask, P, 0);
    gemm_stats<<<256, 256, 0, stream>>>(hbf, wbf, vb, vlt, aL, vArr, mask, P, 256);
    attn<<<512, 256, 0, stream>>>(P, vlt, out);
  }
}

// Round 4
// 166.061 us; speedup vs baseline: 3.3107x; 1.2303x over previous
//
#include <hip/hip_runtime.h>
#include <hip/hip_bf16.h>
#include <stdint.h>

#define LOG2E 1.44269504088896340736f

typedef float f32x4 __attribute__((ext_vector_type(4)));
typedef __bf16 bf16x8 __attribute__((ext_vector_type(8)));

__device__ __forceinline__ void g2lds16(const void* g, void* l) {
  __builtin_amdgcn_global_load_lds(
      (__attribute__((address_space(1))) unsigned int*)g,
      (__attribute__((address_space(3))) unsigned int*)l,
      16, 0, 0);
}

__device__ __forceinline__ unsigned short f2bf_u(float f) {
  __bf16 h = (__bf16)f;
  return __builtin_bit_cast(unsigned short, h);
}

// ---------------------------------------------------------------------------
// fused_prep: 640 blocks (round-0 proven). pid<512: prep_hidden (barrier-free,
// 4 waves x 4 rows, XCD-colocated row mapping). pid>=512: prep_w grid-stride
// bf16 cast.
// ---------------------------------------------------------------------------
__global__ void __launch_bounds__(256) fused_prep(
    const float* __restrict__ hidden, const float* __restrict__ U,
    const float* __restrict__ V, const float* __restrict__ vw,
    unsigned short* __restrict__ hbf, unsigned short* __restrict__ wbf,
    float* __restrict__ aL, float* __restrict__ vArr) {
  int tid = threadIdx.x;
  int pid = blockIdx.x;
  if (pid < 512) {
    int lane = tid & 63, w = tid >> 6;
    int xcd = pid & 7, idx = pid >> 3;
    int row0 = (xcd << 10) + (idx * 4 + w) * 4;
    float4 u4[4], v4[4];
#pragma unroll
    for (int c = 0; c < 4; ++c) {
      u4[c] = *(const float4*)&U[c * 256 + lane * 4];
      v4[c] = *(const float4*)&V[c * 256 + lane * 4];
    }
    float u_t = U[1024], v_t = V[1024];
    float su[4], sv[4];
#pragma unroll
    for (int r = 0; r < 4; ++r) {
      const float* hr = hidden + (size_t)(row0 + r) * 1024;
      unsigned short* hb = hbf + (size_t)(row0 + r) * 1024;
      float ssu = 0.f, ssv = 0.f;
#pragma unroll
      for (int c = 0; c < 4; ++c) {
        float4 x = *(const float4*)&hr[c * 256 + lane * 4];
        ushort4 o;
        o.x = f2bf_u(x.x); o.y = f2bf_u(x.y); o.z = f2bf_u(x.z); o.w = f2bf_u(x.w);
        *(ushort4*)&hb[c * 256 + lane * 4] = o;
        ssu += x.x * u4[c].x + x.y * u4[c].y + x.z * u4[c].z + x.w * u4[c].w;
        ssv += x.x * v4[c].x + x.y * v4[c].y + x.z * v4[c].z + x.w * v4[c].w;
      }
      su[r] = ssu; sv[r] = ssv;
    }
#pragma unroll
    for (int off = 1; off < 64; off <<= 1) {
#pragma unroll
      for (int r = 0; r < 4; ++r) {
        su[r] += __shfl_xor(su[r], off);
        sv[r] += __shfl_xor(sv[r], off);
      }
    }
    if (lane < 4) {
      int r = lane;
      float sur = (r == 0) ? su[0] : (r == 1) ? su[1] : (r == 2) ? su[2] : su[3];
      float svr = (r == 0) ? sv[0] : (r == 1) ? sv[1] : (r == 2) ? sv[2] : sv[3];
      aL[row0 + r] = (sur + u_t) * 0.125f * LOG2E;
      vArr[row0 + r] = svr + v_t;
    }
  } else {
    int wp = pid - 512;
#pragma unroll
    for (int it = 0; it < 8; ++it) {
      int idx = (wp * 256 + tid) * 4 + it * 131072;
      float4 x = *(const float4*)&vw[idx];
      ushort4 o;
      o.x = f2bf_u(x.x); o.y = f2bf_u(x.y); o.z = f2bf_u(x.z); o.w = f2bf_u(x.w);
      *(ushort4*)&wbf[idx] = o;
    }
  }
}

// ---------------------------------------------------------------------------
// gemm_stats: pid < statsBlocks -> statsP (unchanged, proven). pid >= stats ->
// gemm_vl 128x128 tile, NEW K-loop: BK=64, double-buffered LDS (2x16KB per
// operand = same 64KB total), prefetch-next-tile + COUNTED s_waitcnt vmcnt(8)
// + raw s_barrier (no compiler vmcnt(0) drain). 8-chunk XOR swizzle
// (2-way bank aliasing = free, m136). Linear LDS dest + pre-swizzled global
// source per g2lds rules.
// ---------------------------------------------------------------------------
__global__ void __launch_bounds__(256) gemm_stats(
    const unsigned short* __restrict__ hbf, const unsigned short* __restrict__ wbf,
    const float* __restrict__ bias, unsigned short* __restrict__ vlt,
    const float* __restrict__ aL, const float* __restrict__ vArr,
    const float* __restrict__ mask, unsigned short* __restrict__ P,
    int statsBlocks) {
  __shared__ __align__(16) char sA[2][128 * 128];
  __shared__ __align__(16) char sB[2][128 * 128];
  int tid = threadIdx.x;
  int pid = blockIdx.x;
  if (pid >= statsBlocks) {
    int g = pid - statsBlocks;
    int lane = tid & 63, wave = tid >> 6;
    int xcd = g & 7, kk = g >> 3;
    int m0 = (xcd * 8 + (kk >> 3)) * 128;
    int n0 = (kk & 7) * 128;
    int r8 = lane >> 3, c8 = lane & 7;   // staging: row-within-8, chunk
    int wr = wave >> 1, wc = wave & 1;
    int m_ = lane & 15, q = lane >> 4;
    // prologue: stage tile 0 into buf 0
#pragma unroll
    for (int ii = 0; ii < 4; ++ii) {
      int rb = wave * 32 + ii * 8;
      int r = rb + r8;
      int gc = c8 ^ (r & 7);
      g2lds16(hbf + (size_t)(m0 + r) * 1024 + gc * 8, sA[0] + rb * 128);
      g2lds16(wbf + (size_t)(n0 + r) * 1024 + gc * 8, sB[0] + rb * 128);
    }
    f32x4 acc[4][4] = {};
    for (int k = 0; k < 16; ++k) {
      int cur = k & 1;
      if (k < 15) {
        int k0n = (k + 1) * 64;
#pragma unroll
        for (int ii = 0; ii < 4; ++ii) {
          int rb = wave * 32 + ii * 8;
          int r = rb + r8;
          int gc = c8 ^ (r & 7);
          g2lds16(hbf + (size_t)(m0 + r) * 1024 + k0n + gc * 8, sA[cur ^ 1] + rb * 128);
          g2lds16(wbf + (size_t)(n0 + r) * 1024 + k0n + gc * 8, sB[cur ^ 1] + rb * 128);
        }
        asm volatile("s_waitcnt vmcnt(8)" ::: "memory");
      } else {
        asm volatile("s_waitcnt vmcnt(0)" ::: "memory");
      }
      __builtin_amdgcn_s_barrier();
      asm volatile("" ::: "memory");
      const char* ca = sA[cur];
      const char* cb = sB[cur];
#pragma unroll
      for (int ks = 0; ks < 2; ++ks) {
        bf16x8 af[4], bfr[4];
#pragma unroll
        for (int i = 0; i < 4; ++i)
          af[i] = *(const bf16x8*)(ca + (wr * 64 + i * 16 + m_) * 128 + (((ks * 4 + q) ^ (m_ & 7)) * 16));
#pragma unroll
        for (int j = 0; j < 4; ++j)
          bfr[j] = *(const bf16x8*)(cb + (wc * 64 + j * 16 + m_) * 128 + (((ks * 4 + q) ^ (m_ & 7)) * 16));
#pragma unroll
        for (int i = 0; i < 4; ++i)
#pragma unroll
          for (int j = 0; j < 4; ++j)
            acc[i][j] = __builtin_amdgcn_mfma_f32_16x16x32_bf16(af[i], bfr[j], acc[i][j], 0, 0, 0);
      }
      asm volatile("" ::: "memory");
      __builtin_amdgcn_s_barrier();
    }
#pragma unroll
    for (int jt = 0; jt < 4; ++jt) {
      int j = n0 + wc * 64 + jt * 16 + m_;
      float bj = bias[j];
#pragma unroll
      for (int it = 0; it < 4; ++it) {
        int i = m0 + wr * 64 + it * 16 + q * 4;
        f32x4 a = acc[it][jt];
        ushort4 o;
        o.x = f2bf_u(a.x + bj); o.y = f2bf_u(a.y + bj);
        o.z = f2bf_u(a.z + bj); o.w = f2bf_u(a.w + bj);
        *(ushort4*)&vlt[(size_t)j * 8192 + i] = o;
      }
    }
  } else {
    // ---- statsP path: barrier-free, 4 waves x 8 rows, XCD-colocated ----
    int b = pid;
    int lane = tid & 63, w = tid >> 6;
    int xcd = b & 7, idx = b >> 3;
    int row0 = (xcd << 10) + (idx * 4 + w) * 8;
    int tb = (row0 >> 11) << 11;
    float4 va[8], ma[8];
#pragma unroll
    for (int c = 0; c < 4; ++c) {
      int t = c * 512 + lane * 8;
      va[2 * c]     = *(const float4*)&vArr[tb + t];
      va[2 * c + 1] = *(const float4*)&vArr[tb + t + 4];
      float4 m0v = *(const float4*)&mask[tb + t];
      float4 m1v = *(const float4*)&mask[tb + t + 4];
      ma[2 * c].x = m0v.x * LOG2E; ma[2 * c].y = m0v.y * LOG2E;
      ma[2 * c].z = m0v.z * LOG2E; ma[2 * c].w = m0v.w * LOG2E;
      ma[2 * c + 1].x = m1v.x * LOG2E; ma[2 * c + 1].y = m1v.y * LOG2E;
      ma[2 * c + 1].z = m1v.z * LOG2E; ma[2 * c + 1].w = m1v.w * LOG2E;
    }
#pragma unroll
    for (int r = 0; r < 8; ++r) {
      int row = row0 + r;
      float a = aL[row];
      float s[32];
#pragma unroll
      for (int qq = 0; qq < 8; ++qq) {
        s[qq * 4 + 0] = fmaf(a, va[qq].x, ma[qq].x);
        s[qq * 4 + 1] = fmaf(a, va[qq].y, ma[qq].y);
        s[qq * 4 + 2] = fmaf(a, va[qq].z, ma[qq].z);
        s[qq * 4 + 3] = fmaf(a, va[qq].w, ma[qq].w);
      }
      float mx = s[0];
#pragma unroll
      for (int u = 1; u < 32; ++u) mx = fmaxf(mx, s[u]);
#pragma unroll
      for (int off = 1; off < 64; off <<= 1) mx = fmaxf(mx, __shfl_xor(mx, off));
      float z = 0.f;
#pragma unroll
      for (int u = 0; u < 32; ++u) {
        s[u] = __builtin_amdgcn_exp2f(s[u] - mx);
        z += s[u];
      }
#pragma unroll
      for (int off = 1; off < 64; off <<= 1) z += __shfl_xor(z, off);
      float iz = __builtin_amdgcn_rcpf(z);
      unsigned short* pr = P + (size_t)row * 2048;
#pragma unroll
      for (int c = 0; c < 4; ++c) {
        bf16x8 o;
#pragma unroll
        for (int u = 0; u < 8; ++u) o[u] = (__bf16)(iz * s[c * 8 + u]);
        *(bf16x8*)&pr[c * 512 + lane * 8] = o;
      }
    }
  }
}

// ---------------------------------------------------------------------------
// attn: C = P' @ VL^T-slice, K=2048. NEW K-loop: BK=64, double-buffered LDS,
// counted vmcnt(8) prefetch, raw s_barrier (same structure as gemm above).
// 512 blocks, 128x128 tile, XCD swizzle as before.
// ---------------------------------------------------------------------------
__global__ void __launch_bounds__(256) attn(
    const unsigned short* __restrict__ p, const unsigned short* __restrict__ vlt,
    float* __restrict__ out) {
  __shared__ __align__(16) char sA[2][128 * 128];
  __shared__ __align__(16) char sB[2][128 * 128];
  int tid = threadIdx.x;
  int lane = tid & 63, wave = tid >> 6;
  int pid = blockIdx.x;
  int xcd = pid & 7, kk = pid >> 3;
  int i0 = (xcd * 8 + (kk >> 3)) * 128;  // s-row tile (batch-major)
  int h0 = (kk & 7) * 128;               // h tile
  int b = i0 >> 11;
  size_t toff = (size_t)b << 11;
  int r8 = lane >> 3, c8 = lane & 7;
  int wr = wave >> 1, wc = wave & 1;
  int m_ = lane & 15, q = lane >> 4;
  // prologue: stage tile 0 into buf 0
#pragma unroll
  for (int ii = 0; ii < 4; ++ii) {
    int rb = wave * 32 + ii * 8;
    int r = rb + r8;
    int gc = c8 ^ (r & 7);
    g2lds16(p + (size_t)(i0 + r) * 2048 + gc * 8, sA[0] + rb * 128);
    g2lds16(vlt + (size_t)(h0 + r) * 8192 + toff + gc * 8, sB[0] + rb * 128);
  }
  f32x4 acc[4][4] = {};
  for (int k = 0; k < 32; ++k) {
    int cur = k & 1;
    if (k < 31) {
      int k0n = (k + 1) * 64;
#pragma unroll
      for (int ii = 0; ii < 4; ++ii) {
        int rb = wave * 32 + ii * 8;
        int r = rb + r8;
        int gc = c8 ^ (r & 7);
        g2lds16(p + (size_t)(i0 + r) * 2048 + k0n + gc * 8, sA[cur ^ 1] + rb * 128);
        g2lds16(vlt + (size_t)(h0 + r) * 8192 + toff + k0n + gc * 8, sB[cur ^ 1] + rb * 128);
      }
      asm volatile("s_waitcnt vmcnt(8)" ::: "memory");
    } else {
      asm volatile("s_waitcnt vmcnt(0)" ::: "memory");
    }
    __builtin_amdgcn_s_barrier();
    asm volatile("" ::: "memory");
    const char* ca = sA[cur];
    const char* cb = sB[cur];
#pragma unroll
    for (int ks = 0; ks < 2; ++ks) {
      bf16x8 af[4], bfr[4];
#pragma unroll
      for (int i = 0; i < 4; ++i)
        af[i] = *(const bf16x8*)(ca + (wr * 64 + i * 16 + m_) * 128 + (((ks * 4 + q) ^ (m_ & 7)) * 16));
#pragma unroll
      for (int j = 0; j < 4; ++j)
        bfr[j] = *(const bf16x8*)(cb + (wc * 64 + j * 16 + m_) * 128 + (((ks * 4 + q) ^ (m_ & 7)) * 16));
#pragma unroll
      for (int i = 0; i < 4; ++i)
#pragma unroll
        for (int j = 0; j < 4; ++j)
          acc[i][j] = __builtin_amdgcn_mfma_f32_16x16x32_bf16(af[i], bfr[j], acc[i][j], 0, 0, 0);
    }
    asm volatile("" ::: "memory");
    __builtin_amdgcn_s_barrier();
  }
#pragma unroll
  for (int it = 0; it < 4; ++it) {
    int gi = i0 + wr * 64 + it * 16 + q * 4;
#pragma unroll
    for (int jt = 0; jt < 4; ++jt) {
      int h = h0 + wc * 64 + jt * 16 + m_;
      f32x4 a = acc[it][jt];
      out[(size_t)(gi + 0) * 1024 + h] = a.x;
      out[(size_t)(gi + 1) * 1024 + h] = a.y;
      out[(size_t)(gi + 2) * 1024 + h] = a.z;
      out[(size_t)(gi + 3) * 1024 + h] = a.w;
    }
  }
}

// ---------------------------------------------------------------------------
// Layout A (ws >= 69.3 MB, 3 launches; P disjoint so statsP overlaps gemm):
//   hbf 0..16MB | wbf 16..18MB | vlt 18..34.8MB | P 34.8..68.3MB | aL,vArr
// Layout B (fallback, 4 launches; P overlaps dead hbf/wbf).
// ---------------------------------------------------------------------------
extern "C" void kernel_launch(void* const* d_in, const int* in_sizes, int n_in,
                              void* d_out, int out_size, void* d_ws, size_t ws_size,
                              hipStream_t stream) {
  const float* hidden = (const float*)d_in[0];
  const float* mask   = (const float*)d_in[1];
  const float* vw     = (const float*)d_in[2];
  const float* vb     = (const float*)d_in[3];
  const float* U      = (const float*)d_in[4];
  const float* V      = (const float*)d_in[5];
  float* out = (float*)d_out;
  char* ws = (char*)d_ws;

  if (ws_size >= 69271552ull) {
    unsigned short* hbf = (unsigned short*)ws;
    unsigned short* wbf = (unsigned short*)(ws + 16777216);
    unsigned short* vlt = (unsigned short*)(ws + 18874368);
    unsigned short* P   = (unsigned short*)(ws + 35651584);
    float* aL   = (float*)(ws + 69206016);
    float* vArr = aL + 8192;
    fused_prep<<<640, 256, 0, stream>>>(hidden, U, V, vw, hbf, wbf, aL, vArr);
    gemm_stats<<<768, 256, 0, stream>>>(hbf, wbf, vb, vlt, aL, vArr, mask, P, 256);
    attn<<<512, 256, 0, stream>>>(P, vlt, out);
  } else {
    unsigned short* hbf = (unsigned short*)ws;
    unsigned short* wbf = (unsigned short*)(ws + 16777216);
    unsigned short* P   = (unsigned short*)ws;               // overlaps dead hbf/wbf
    unsigned short* vlt = (unsigned short*)(ws + 33554432);
    float* aL   = (float*)(ws + 50331648);
    float* vArr = aL + 8192;
    fused_prep<<<640, 256, 0, stream>>>(hidden, U, V, vw, hbf, wbf, aL, vArr);
    gemm_stats<<<512, 256, 0, stream>>>(hbf, wbf, vb, vlt, aL, vArr, mask, P, 0);
    gemm_stats<<<256, 256, 0, stream>>>(hbf, wbf, vb, vlt, aL, vArr, mask, P, 256);
    attn<<<512, 256, 0, stream>>>(P, vlt, out);
  }
}